// Round 1
// baseline (580.111 us; speedup 1.0000x reference)
//
#include <hip/hip_runtime.h>
#include <hip/hip_bf16.h>
#include <stdint.h>

// ---- types ----
typedef float   floatx4  __attribute__((ext_vector_type(4)));
typedef __bf16  bf16x8   __attribute__((ext_vector_type(8)));
typedef _Float16 halfx8  __attribute__((ext_vector_type(8)));
typedef unsigned short ushortx8 __attribute__((ext_vector_type(8)));

#define NROW 8192
#define NDIM 2048
#define BM 128
#define BN 128
#define BK 32
#define CT 8            // col tiles (of BN) per block => col range = 1024
#define DT_LD 136       // Dt row stride in halves: 16B-aligned, not pow2 (bank spread)
#define KLISTS 16       // partial 5-lists per row: 8 cranges x 2 halves

__device__ __forceinline__ unsigned short f2bf(float f) {
    union { float f; unsigned u; } x; x.f = f;
    unsigned r = x.u + 0x7fffu + ((x.u >> 16) & 1u);   // RNE
    return (unsigned short)(r >> 16);
}

// insert v into descending-sorted a[5] (keeps 5 largest)
__device__ __forceinline__ void ins_desc(float (&a)[5], float v) {
#pragma unroll
    for (int k = 0; k < 5; ++k) { float hi = fmaxf(a[k], v); float lo = fminf(a[k], v); a[k] = hi; v = lo; }
}
// insert v into ascending-sorted a[5] (keeps 5 smallest)
__device__ __forceinline__ void ins_asc(float (&a)[5], float v) {
#pragma unroll
    for (int k = 0; k < 5; ++k) { float lo = fminf(a[k], v); float hi = fmaxf(a[k], v); a[k] = lo; v = hi; }
}

__device__ __forceinline__ void load_lds16(const void* g, void* l) {
    // async global->LDS, 16B/lane, dest = wave-uniform base + lane*16
    __builtin_amdgcn_global_load_lds((__attribute__((address_space(1))) void*)(void*)g,
                                     (__attribute__((address_space(3))) void*)l,
                                     16, 0, 0);
}

// ---- kernel 1: L2 normalize rows, write bf16 matrix + sq (=sum x^2 after norm) ----
__global__ __launch_bounds__(256) void k_normalize(const float* __restrict__ feats,
                                                   unsigned short* __restrict__ xb,
                                                   float* __restrict__ sq) {
    const int row = blockIdx.x;
    const int t = threadIdx.x;
    const float* f = feats + (size_t)row * NDIM + t * 8;
    float4 v0 = *(const float4*)(f);
    float4 v1 = *(const float4*)(f + 4);
    float ss = v0.x*v0.x + v0.y*v0.y + v0.z*v0.z + v0.w*v0.w
             + v1.x*v1.x + v1.y*v1.y + v1.z*v1.z + v1.w*v1.w;
#pragma unroll
    for (int o = 32; o > 0; o >>= 1) ss += __shfl_down(ss, o);
    __shared__ float red[4];
    __shared__ float s_inv;
    if ((t & 63) == 0) red[t >> 6] = ss;
    __syncthreads();
    if (t == 0) {
        float tot = red[0] + red[1] + red[2] + red[3];
        float m = fmaxf(sqrtf(tot), 1e-12f);
        float inv = 1.0f / m;
        sq[row] = tot * inv * inv;
        s_inv = inv;
    }
    __syncthreads();
    float inv = s_inv;
    float vv[8] = {v0.x, v0.y, v0.z, v0.w, v1.x, v1.y, v1.z, v1.w};
    ushortx8 u;
#pragma unroll
    for (int e = 0; e < 8; ++e) u[e] = f2bf(vv[e] * inv);
    *(ushortx8*)(xb + (size_t)row * NDIM + t * 8) = u;
}

// ---- kernel 2: fused bf16 MFMA GEMM (x x^T) + dist + masked running top-5 ----
// grid: 512 blocks; strip = bx>>3 (row strip of 128), crange = bx&7 (1024 cols)
__global__ __launch_bounds__(256, 2) void k_gemm_topk(
        const unsigned short* __restrict__ xb, const float* __restrict__ sq,
        const int* __restrict__ labels, const int* __restrict__ camids,
        float* __restrict__ pos_part, float* __restrict__ neg_part) {
    __shared__ unsigned short As[BM * BK];         // [row][k], 8 KB
    __shared__ unsigned short Bs[BN * BK];         // [col-row][k], 8 KB
    __shared__ _Float16 Dt[BM * DT_LD];            // dist tile, 34 KB
    __shared__ float sqr_s[BM], sqc_s[BN];
    __shared__ int labr[BM], camr[BM], labc[BN], camc[BN];

    const int tid = threadIdx.x;
    const int w = tid >> 6, lane = tid & 63;
    const int wm = w >> 1, wn = w & 1;
    const int strip = blockIdx.x >> 3;
    const int crange = blockIdx.x & 7;
    const int r0 = strip * BM;
    const int cb0 = crange * (BN * CT);

    if (tid < BM) {
        int gi = r0 + tid;
        sqr_s[tid] = sq[gi]; labr[tid] = labels[gi]; camr[tid] = camids[gi];
    }
    __syncthreads();

    const int srow = tid >> 1;       // scan: 2 threads per row
    const int shalf = tid & 1;
    const int li = labr[srow], ci = camr[srow];

    const float NINF = -__builtin_inff();
    const float PINF =  __builtin_inff();
    float pos5[5] = {NINF, NINF, NINF, NINF, NINF};
    float neg5[5] = {PINF, PINF, PINF, PINF, PINF};

    const int lr = lane >> 2;        // staging: lane -> row within 16-row chunk
    const int lc = (lane & 3) * 8;   // staging: lane -> k offset (8 bf16 = 16B)
    const int m16 = lane & 15;
    const int quad = lane >> 4;

    for (int ct = 0; ct < CT; ++ct) {
        const int cb = cb0 + ct * BN;
        if (tid < BN) {              // safe: previous scan ended with barrier
            int gj = cb + tid;
            sqc_s[tid] = sq[gj]; labc[tid] = labels[gj]; camc[tid] = camids[gj];
        }
        floatx4 acc[4][4];
#pragma unroll
        for (int mi = 0; mi < 4; ++mi)
#pragma unroll
            for (int ni = 0; ni < 4; ++ni) {
                floatx4 z = {0.f, 0.f, 0.f, 0.f};
                acc[mi][ni] = z;
            }

        for (int kk = 0; kk < NDIM; kk += BK) {
            __syncthreads();         // previous tile's LDS consumers done
#pragma unroll
            for (int q = 0; q < 2; ++q) {
                const int ra = q * 64 + w * 16;   // wave-uniform chunk base
                load_lds16(xb + (size_t)(r0 + ra + lr) * NDIM + kk + lc, As + ra * BK);
                load_lds16(xb + (size_t)(cb + ra + lr) * NDIM + kk + lc, Bs + ra * BK);
            }
            __syncthreads();         // drains vmcnt(0): data in LDS
            bf16x8 af[4], bfr[4];
#pragma unroll
            for (int mi = 0; mi < 4; ++mi)
                af[mi] = *(const bf16x8*)(As + (wm * 64 + mi * 16 + m16) * BK + quad * 8);
#pragma unroll
            for (int ni = 0; ni < 4; ++ni)
                bfr[ni] = *(const bf16x8*)(Bs + (wn * 64 + ni * 16 + m16) * BK + quad * 8);
#pragma unroll
            for (int mi = 0; mi < 4; ++mi)
#pragma unroll
                for (int ni = 0; ni < 4; ++ni)
                    acc[mi][ni] = __builtin_amdgcn_mfma_f32_16x16x32_bf16(af[mi], bfr[ni], acc[mi][ni], 0, 0, 0);
        }

        // epilogue: dot -> dist (fp16) into Dt.  C layout: col=lane&15, row=quad*4+reg
#pragma unroll
        for (int mi = 0; mi < 4; ++mi) {
            const int il = wm * 64 + mi * 16 + quad * 4;
#pragma unroll
            for (int ni = 0; ni < 4; ++ni) {
                const int jl = wn * 64 + ni * 16 + m16;
                const float sj = sqc_s[jl];
#pragma unroll
                for (int r = 0; r < 4; ++r) {
                    float d2 = sqr_s[il + r] + sj - 2.0f * acc[mi][ni][r];
                    Dt[(il + r) * DT_LD + jl] = (_Float16)sqrtf(fmaxf(d2, 1e-12f));
                }
            }
        }
        __syncthreads();

        // scan: thread (srow, shalf) scans 64 cols, updates running top-5s
        const int jb = shalf * 64;
#pragma unroll
        for (int c8 = 0; c8 < 8; ++c8) {
            halfx8 v = *(const halfx8*)(Dt + srow * DT_LD + jb + c8 * 8);
#pragma unroll
            for (int e = 0; e < 8; ++e) {
                const int jl = jb + c8 * 8 + e;
                float dist = (float)v[e];
                int lj = labc[jl], cj = camc[jl];
                if (lj == li) {
                    // positive: same label, cross-cam (i==j auto-excluded: same cam)
                    if (cj != ci && dist > pos5[4]) ins_desc(pos5, dist);
                } else {
                    // negative: different label (i==j auto-excluded: same label)
                    float vn = (cj == ci) ? dist * (1.0f / 1.2f) : dist;
                    if (vn < neg5[4]) ins_asc(neg5, vn);
                }
            }
        }
        __syncthreads();
    }

    const int gi = r0 + srow;
    float* pp = pos_part + ((size_t)gi * KLISTS + crange * 2 + shalf) * 5;
    float* np = neg_part + ((size_t)gi * KLISTS + crange * 2 + shalf) * 5;
#pragma unroll
    for (int k = 0; k < 5; ++k) { pp[k] = pos5[k]; np[k] = neg5[k]; }
}

// ---- kernel 3: merge 16 partial lists/row -> d_ap, d_an, w0, per_sample; block partials ----
__global__ __launch_bounds__(256) void k_merge(const float* __restrict__ pos_part,
        const float* __restrict__ neg_part, const int* __restrict__ epoch_p,
        float* __restrict__ out, float* __restrict__ wsum_p, float* __restrict__ wpsum_p) {
    const int row = blockIdx.x * 256 + threadIdx.x;
    const float NINF = -__builtin_inff(), PINF = __builtin_inff();
    float p5[5] = {NINF, NINF, NINF, NINF, NINF};
    float n5[5] = {PINF, PINF, PINF, PINF, PINF};
    const float* pp = pos_part + (size_t)row * (KLISTS * 5);
    const float* np = neg_part + (size_t)row * (KLISTS * 5);
    for (int k = 0; k < KLISTS * 5; ++k) {
        float v = pp[k];
        if (v > p5[4]) ins_desc(p5, v);
    }
    for (int k = 0; k < KLISTS * 5; ++k) {
        float v = np[k];
        if (v < n5[4]) ins_asc(n5, v);
    }
    float s = 0.f; int c = 0;
#pragma unroll
    for (int k = 0; k < 5; ++k) { bool fin = (p5[k] > NINF); s += fin ? p5[k] : 0.f; c += fin ? 1 : 0; }
    float d_ap = (c > 0) ? s / (float)c : NINF;          // fallback = max(work) = -inf
    s = 0.f; c = 0;
#pragma unroll
    for (int k = 0; k < 5; ++k) { bool fin = (n5[k] < PINF); s += fin ? n5[k] : 0.f; c += fin ? 1 : 0; }
    float d_an = (c > 0) ? s / (float)c : PINF;          // fallback = min(work) = +inf

    out[1 + row] = d_ap;
    out[1 + NROW + row] = d_an;

    float diff = d_ap - d_an;                            // never NaN (d_ap!=+inf, d_an!=-inf)
    float w0 = 1.0f / (1.0f + expf(-2.0f * diff));       // sigmoid(ALPHA*(d_ap-d_an))
    float p;
    if (*epoch_p < 10) {
        p = fmaxf(diff, 0.0f) + log1pf(expf(-fabsf(diff)));  // stable softplus(diff)
    } else {
        p = fmaxf(diff + 0.3f, 0.0f);                    // relu(d_ap - d_an + MARGIN)
    }
    float wp = w0 * p;
#pragma unroll
    for (int o = 32; o > 0; o >>= 1) { w0 += __shfl_down(w0, o); wp += __shfl_down(wp, o); }
    __shared__ float rw[4], rp[4];
    const int t = threadIdx.x;
    if ((t & 63) == 0) { rw[t >> 6] = w0; rp[t >> 6] = wp; }
    __syncthreads();
    if (t == 0) {
        wsum_p[blockIdx.x]  = rw[0] + rw[1] + rw[2] + rw[3];
        wpsum_p[blockIdx.x] = rp[0] + rp[1] + rp[2] + rp[3];
    }
}

// ---- kernel 4: finalize loss scalar ----
__global__ void k_finalize(const float* __restrict__ wsum_p, const float* __restrict__ wpsum_p,
                           float* __restrict__ out) {
    if (threadIdx.x == 0) {
        float sw = 0.f, swp = 0.f;
        for (int i = 0; i < 32; ++i) { sw += wsum_p[i]; swp += wpsum_p[i]; }
        float M = fmaxf(sw / (float)NROW, 1e-12f);
        out[0] = swp / ((float)NROW * M);
    }
}

extern "C" void kernel_launch(void* const* d_in, const int* in_sizes, int n_in,
                              void* d_out, int out_size, void* d_ws, size_t ws_size,
                              hipStream_t stream) {
    const float* feats  = (const float*)d_in[0];
    const int*   labels = (const int*)d_in[1];
    const int*   camids = (const int*)d_in[2];
    const int*   epoch  = (const int*)d_in[3];
    float* out = (float*)d_out;
    char* ws = (char*)d_ws;
    // workspace layout (~38.8 MB total)
    unsigned short* xb = (unsigned short*)ws;                              // 33,554,432 B
    float* sq        = (float*)(ws + 33554432);                            //     32,768 B
    float* pos_part  = (float*)(ws + 33554432 + 32768);                    //  2,621,440 B
    float* neg_part  = (float*)(ws + 33554432 + 32768 + 2621440);          //  2,621,440 B
    float* wsum_p    = (float*)(ws + 33554432 + 32768 + 2u * 2621440);     //        128 B
    float* wpsum_p   = wsum_p + 32;                                        //        128 B

    k_normalize<<<NROW, 256, 0, stream>>>(feats, xb, sq);
    k_gemm_topk<<<512, 256, 0, stream>>>(xb, sq, labels, camids, pos_part, neg_part);
    k_merge<<<NROW / 256, 256, 0, stream>>>(pos_part, neg_part, epoch, out, wsum_p, wpsum_p);
    k_finalize<<<1, 64, 0, stream>>>(wsum_p, wpsum_p, out);
}

// Round 2
// 562.098 us; speedup vs baseline: 1.0320x; 1.0320x over previous
//
#include <hip/hip_runtime.h>
#include <hip/hip_bf16.h>
#include <stdint.h>

// ---- types ----
typedef float   floatx4  __attribute__((ext_vector_type(4)));
typedef __bf16  bf16x8   __attribute__((ext_vector_type(8)));
typedef _Float16 halfx8  __attribute__((ext_vector_type(8)));
typedef unsigned short ushortx8 __attribute__((ext_vector_type(8)));

#define NROW 8192
#define NDIM 2048
#define BM 128
#define BN 128
#define BK 32
#define CT 8            // col tiles (of BN) per block => col range = 1024
#define DT_LD 136       // Dt row stride in halves (272 B: 16B-aligned b128 reads)
#define KLISTS 16       // partial 5-lists per row: 8 cranges x 2 halves

__device__ __forceinline__ unsigned short f2bf(float f) {
    union { float f; unsigned u; } x; x.f = f;
    unsigned r = x.u + 0x7fffu + ((x.u >> 16) & 1u);   // RNE
    return (unsigned short)(r >> 16);
}

// insert v into descending-sorted a[5] (keeps 5 largest)
__device__ __forceinline__ void ins_desc(float (&a)[5], float v) {
#pragma unroll
    for (int k = 0; k < 5; ++k) { float hi = fmaxf(a[k], v); float lo = fminf(a[k], v); a[k] = hi; v = lo; }
}
// insert v into ascending-sorted a[5] (keeps 5 smallest)
__device__ __forceinline__ void ins_asc(float (&a)[5], float v) {
#pragma unroll
    for (int k = 0; k < 5; ++k) { float lo = fminf(a[k], v); float hi = fmaxf(a[k], v); a[k] = lo; v = hi; }
}

__device__ __forceinline__ void load_lds16(const void* g, void* l) {
    // async global->LDS, 16B/lane, dest = wave-uniform base + lane*16
    __builtin_amdgcn_global_load_lds((__attribute__((address_space(1))) void*)(void*)g,
                                     (__attribute__((address_space(3))) void*)l,
                                     16, 0, 0);
}

// ---- kernel 1: L2 normalize rows, write bf16 matrix + sq (=sum x^2 after norm) ----
__global__ __launch_bounds__(256) void k_normalize(const float* __restrict__ feats,
                                                   unsigned short* __restrict__ xb,
                                                   float* __restrict__ sq) {
    const int row = blockIdx.x;
    const int t = threadIdx.x;
    const float* f = feats + (size_t)row * NDIM + t * 8;
    float4 v0 = *(const float4*)(f);
    float4 v1 = *(const float4*)(f + 4);
    float ss = v0.x*v0.x + v0.y*v0.y + v0.z*v0.z + v0.w*v0.w
             + v1.x*v1.x + v1.y*v1.y + v1.z*v1.z + v1.w*v1.w;
#pragma unroll
    for (int o = 32; o > 0; o >>= 1) ss += __shfl_down(ss, o);
    __shared__ float red[4];
    __shared__ float s_inv;
    if ((t & 63) == 0) red[t >> 6] = ss;
    __syncthreads();
    if (t == 0) {
        float tot = red[0] + red[1] + red[2] + red[3];
        float m = fmaxf(sqrtf(tot), 1e-12f);
        float inv = 1.0f / m;
        sq[row] = tot * inv * inv;
        s_inv = inv;
    }
    __syncthreads();
    float inv = s_inv;
    float vv[8] = {v0.x, v0.y, v0.z, v0.w, v1.x, v1.y, v1.z, v1.w};
    ushortx8 u;
#pragma unroll
    for (int e = 0; e < 8; ++e) u[e] = f2bf(vv[e] * inv);
    *(ushortx8*)(xb + (size_t)row * NDIM + t * 8) = u;
}

// ---- kernel 2: fused bf16 MFMA GEMM (x x^T) + dist + masked running top-5 ----
// grid: 512 blocks; strip = bx>>3 (row strip of 128), crange = bx&7 (1024 cols)
// LDS: As/Bs (16 KB, live during K-loop) UNIONED with Dt (34.8 KB, live during
// epilogue+scan) -> 36 KB total -> 4 blocks/CU (was 54 KB -> 2 blocks/CU).
__global__ __launch_bounds__(256, 4) void k_gemm_topk(
        const unsigned short* __restrict__ xb, const float* __restrict__ sq,
        const int* __restrict__ labels, const int* __restrict__ camids,
        float* __restrict__ pos_part, float* __restrict__ neg_part) {
    __shared__ __align__(16) char smem[BM * DT_LD * 2 + 2 * BM * 4 + 2 * BM * 4];
    unsigned short* As = (unsigned short*)smem;            // [0, 8192)
    unsigned short* Bs = (unsigned short*)(smem + BM * BK * 2); // [8192, 16384)
    _Float16* Dt = (_Float16*)smem;                        // [0, 34816)  (aliases As/Bs)
    float* sqr_s = (float*)(smem + BM * DT_LD * 2);        // +512
    float* sqc_s = sqr_s + BM;                             // +512
    int* labcam_r = (int*)(sqc_s + BN);                    // +512 (label<<4 | cam)
    int* labcam_c = labcam_r + BM;                         // +512

    const int tid = threadIdx.x;
    const int w = tid >> 6, lane = tid & 63;
    const int wm = w >> 1, wn = w & 1;
    const int strip = blockIdx.x >> 3;
    const int crange = blockIdx.x & 7;
    const int r0 = strip * BM;
    const int cb0 = crange * (BN * CT);

    if (tid < BM) {
        int gi = r0 + tid;
        sqr_s[tid] = sq[gi];
        labcam_r[tid] = (labels[gi] << 4) | camids[gi];
    }
    __syncthreads();

    const int srow = tid >> 1;       // scan: 2 threads per row
    const int shalf = tid & 1;
    const int pli = labcam_r[srow];

    const float NINF = -__builtin_inff();
    const float PINF =  __builtin_inff();
    float pos5[5] = {NINF, NINF, NINF, NINF, NINF};
    float neg5[5] = {PINF, PINF, PINF, PINF, PINF};

    const int lr = lane >> 2;        // staging: lane -> row within 16-row chunk
    const int lc = (lane & 3) * 8;   // staging: lane -> k offset (8 bf16 = 16B)
    const int m16 = lane & 15;
    const int quad = lane >> 4;

    for (int ct = 0; ct < CT; ++ct) {
        const int cb = cb0 + ct * BN;
        if (tid < BN) {              // safe: previous scan ended with barrier
            int gj = cb + tid;
            sqc_s[tid] = sq[gj];
            labcam_c[tid] = (labels[gj] << 4) | camids[gj];
        }
        floatx4 acc[4][4];
#pragma unroll
        for (int mi = 0; mi < 4; ++mi)
#pragma unroll
            for (int ni = 0; ni < 4; ++ni) {
                floatx4 z = {0.f, 0.f, 0.f, 0.f};
                acc[mi][ni] = z;
            }

        for (int kk = 0; kk < NDIM; kk += BK) {
            __syncthreads();         // previous tile's LDS consumers done
#pragma unroll
            for (int q = 0; q < 2; ++q) {
                const int ra = q * 64 + w * 16;   // wave-uniform chunk base
                load_lds16(xb + (size_t)(r0 + ra + lr) * NDIM + kk + lc, As + ra * BK);
                load_lds16(xb + (size_t)(cb + ra + lr) * NDIM + kk + lc, Bs + ra * BK);
            }
            __syncthreads();         // drains vmcnt(0): data in LDS
            bf16x8 af[4], bfr[4];
#pragma unroll
            for (int mi = 0; mi < 4; ++mi)
                af[mi] = *(const bf16x8*)(As + (wm * 64 + mi * 16 + m16) * BK + quad * 8);
#pragma unroll
            for (int ni = 0; ni < 4; ++ni)
                bfr[ni] = *(const bf16x8*)(Bs + (wn * 64 + ni * 16 + m16) * BK + quad * 8);
#pragma unroll
            for (int mi = 0; mi < 4; ++mi)
#pragma unroll
                for (int ni = 0; ni < 4; ++ni)
                    acc[mi][ni] = __builtin_amdgcn_mfma_f32_16x16x32_bf16(af[mi], bfr[ni], acc[mi][ni], 0, 0, 0);
        }
        __syncthreads();             // all ds_reads of As/Bs done before Dt overwrite

        // epilogue: dot -> dist (fp16) into Dt.  C layout: col=lane&15, row=quad*4+reg
#pragma unroll
        for (int mi = 0; mi < 4; ++mi) {
            const int il = wm * 64 + mi * 16 + quad * 4;
#pragma unroll
            for (int ni = 0; ni < 4; ++ni) {
                const int jl = wn * 64 + ni * 16 + m16;
                const float sj = sqc_s[jl];
#pragma unroll
                for (int r = 0; r < 4; ++r) {
                    float d2 = sqr_s[il + r] + sj - 2.0f * acc[mi][ni][r];
                    Dt[(il + r) * DT_LD + jl] = (_Float16)__builtin_amdgcn_sqrtf(fmaxf(d2, 1e-12f));
                }
            }
        }
        __syncthreads();

        // scan: thread (srow, shalf) scans 64 cols, updates running top-5s
        const int jb = shalf * 64;
#pragma unroll
        for (int c8 = 0; c8 < 8; ++c8) {
            halfx8 v = *(const halfx8*)(Dt + srow * DT_LD + jb + c8 * 8);
            int4 lc0 = *(const int4*)(labcam_c + jb + c8 * 8);
            int4 lc1 = *(const int4*)(labcam_c + jb + c8 * 8 + 4);
            int lcv[8] = {lc0.x, lc0.y, lc0.z, lc0.w, lc1.x, lc1.y, lc1.z, lc1.w};
#pragma unroll
            for (int e = 0; e < 8; ++e) {
                float dist = (float)v[e];
                int x = pli ^ lcv[e];
                bool same_label = (x & ~15) == 0;
                bool same_cam   = (x & 15) == 0;
                if (same_label) {
                    // positive: same label, cross-cam (i==j auto-excluded: same cam)
                    if (!same_cam && dist > pos5[4]) ins_desc(pos5, dist);
                } else {
                    // negative: different label (i==j auto-excluded: same label)
                    float vn = same_cam ? dist * (1.0f / 1.2f) : dist;
                    if (vn < neg5[4]) ins_asc(neg5, vn);
                }
            }
        }
        __syncthreads();
    }

    const int gi = r0 + srow;
    float* pp = pos_part + ((size_t)gi * KLISTS + crange * 2 + shalf) * 5;
    float* np = neg_part + ((size_t)gi * KLISTS + crange * 2 + shalf) * 5;
#pragma unroll
    for (int k = 0; k < 5; ++k) { pp[k] = pos5[k]; np[k] = neg5[k]; }
}

// ---- kernel 3: merge 16 partial lists/row -> d_ap, d_an, w0, per_sample; block partials ----
__global__ __launch_bounds__(256) void k_merge(const float* __restrict__ pos_part,
        const float* __restrict__ neg_part, const int* __restrict__ epoch_p,
        float* __restrict__ out, float* __restrict__ wsum_p, float* __restrict__ wpsum_p) {
    const int row = blockIdx.x * 256 + threadIdx.x;
    const float NINF = -__builtin_inff(), PINF = __builtin_inff();
    float p5[5] = {NINF, NINF, NINF, NINF, NINF};
    float n5[5] = {PINF, PINF, PINF, PINF, PINF};
    const float* pp = pos_part + (size_t)row * (KLISTS * 5);
    const float* np = neg_part + (size_t)row * (KLISTS * 5);
    for (int k = 0; k < KLISTS * 5; ++k) {
        float v = pp[k];
        if (v > p5[4]) ins_desc(p5, v);
    }
    for (int k = 0; k < KLISTS * 5; ++k) {
        float v = np[k];
        if (v < n5[4]) ins_asc(n5, v);
    }
    float s = 0.f; int c = 0;
#pragma unroll
    for (int k = 0; k < 5; ++k) { bool fin = (p5[k] > NINF); s += fin ? p5[k] : 0.f; c += fin ? 1 : 0; }
    float d_ap = (c > 0) ? s / (float)c : NINF;          // fallback = max(work) = -inf
    s = 0.f; c = 0;
#pragma unroll
    for (int k = 0; k < 5; ++k) { bool fin = (n5[k] < PINF); s += fin ? n5[k] : 0.f; c += fin ? 1 : 0; }
    float d_an = (c > 0) ? s / (float)c : PINF;          // fallback = min(work) = +inf

    out[1 + row] = d_ap;
    out[1 + NROW + row] = d_an;

    float diff = d_ap - d_an;                            // never NaN (d_ap!=+inf, d_an!=-inf)
    float w0 = 1.0f / (1.0f + expf(-2.0f * diff));       // sigmoid(ALPHA*(d_ap-d_an))
    float p;
    if (*epoch_p < 10) {
        p = fmaxf(diff, 0.0f) + log1pf(expf(-fabsf(diff)));  // stable softplus(diff)
    } else {
        p = fmaxf(diff + 0.3f, 0.0f);                    // relu(d_ap - d_an + MARGIN)
    }
    float wp = w0 * p;
#pragma unroll
    for (int o = 32; o > 0; o >>= 1) { w0 += __shfl_down(w0, o); wp += __shfl_down(wp, o); }
    __shared__ float rw[4], rp[4];
    const int t = threadIdx.x;
    if ((t & 63) == 0) { rw[t >> 6] = w0; rp[t >> 6] = wp; }
    __syncthreads();
    if (t == 0) {
        wsum_p[blockIdx.x]  = rw[0] + rw[1] + rw[2] + rw[3];
        wpsum_p[blockIdx.x] = rp[0] + rp[1] + rp[2] + rp[3];
    }
}

// ---- kernel 4: finalize loss scalar ----
__global__ void k_finalize(const float* __restrict__ wsum_p, const float* __restrict__ wpsum_p,
                           float* __restrict__ out) {
    if (threadIdx.x == 0) {
        float sw = 0.f, swp = 0.f;
        for (int i = 0; i < 32; ++i) { sw += wsum_p[i]; swp += wpsum_p[i]; }
        float M = fmaxf(sw / (float)NROW, 1e-12f);
        out[0] = swp / ((float)NROW * M);
    }
}

extern "C" void kernel_launch(void* const* d_in, const int* in_sizes, int n_in,
                              void* d_out, int out_size, void* d_ws, size_t ws_size,
                              hipStream_t stream) {
    const float* feats  = (const float*)d_in[0];
    const int*   labels = (const int*)d_in[1];
    const int*   camids = (const int*)d_in[2];
    const int*   epoch  = (const int*)d_in[3];
    float* out = (float*)d_out;
    char* ws = (char*)d_ws;
    // workspace layout (~38.8 MB total)
    unsigned short* xb = (unsigned short*)ws;                              // 33,554,432 B
    float* sq        = (float*)(ws + 33554432);                            //     32,768 B
    float* pos_part  = (float*)(ws + 33554432 + 32768);                    //  2,621,440 B
    float* neg_part  = (float*)(ws + 33554432 + 32768 + 2621440);          //  2,621,440 B
    float* wsum_p    = (float*)(ws + 33554432 + 32768 + 2u * 2621440);     //        128 B
    float* wpsum_p   = wsum_p + 32;                                        //        128 B

    k_normalize<<<NROW, 256, 0, stream>>>(feats, xb, sq);
    k_gemm_topk<<<512, 256, 0, stream>>>(xb, sq, labels, camids, pos_part, neg_part);
    k_merge<<<NROW / 256, 256, 0, stream>>>(pos_part, neg_part, epoch, out, wsum_p, wpsum_p);
    k_finalize<<<1, 64, 0, stream>>>(wsum_p, wpsum_p, out);
}

// Round 3
// 485.475 us; speedup vs baseline: 1.1949x; 1.1578x over previous
//
#include <hip/hip_runtime.h>
#include <hip/hip_bf16.h>
#include <stdint.h>

// ---- types ----
typedef float   floatx4  __attribute__((ext_vector_type(4)));
typedef __bf16  bf16x8   __attribute__((ext_vector_type(8)));
typedef _Float16 halfx8  __attribute__((ext_vector_type(8)));
typedef unsigned short ushortx8 __attribute__((ext_vector_type(8)));

#define NROW 8192
#define NDIM 2048
#define BM 128
#define BN 128
#define BK 32
#define CT 4            // col tiles (of BN) per block => col range = 512
#define NCR 16          // col ranges = NROW/(BN*CT); grid = 64*NCR = 1024 = 4 blocks/CU
#define DT_LD 136       // Dt row stride in halves (272 B: 16B-aligned b128 reads)
#define KLISTS 16       // partial 5-lists per row: 16 cranges x 1 (halves merged in-kernel)

__device__ __forceinline__ unsigned short f2bf(float f) {
    union { float f; unsigned u; } x; x.f = f;
    unsigned r = x.u + 0x7fffu + ((x.u >> 16) & 1u);   // RNE
    return (unsigned short)(r >> 16);
}

// insert v into descending-sorted a[5] (keeps 5 largest)
__device__ __forceinline__ void ins_desc(float (&a)[5], float v) {
#pragma unroll
    for (int k = 0; k < 5; ++k) { float hi = fmaxf(a[k], v); float lo = fminf(a[k], v); a[k] = hi; v = lo; }
}
// insert v into ascending-sorted a[5] (keeps 5 smallest)
__device__ __forceinline__ void ins_asc(float (&a)[5], float v) {
#pragma unroll
    for (int k = 0; k < 5; ++k) { float lo = fminf(a[k], v); float hi = fmaxf(a[k], v); a[k] = lo; v = hi; }
}

__device__ __forceinline__ void load_lds16(const void* g, void* l) {
    // async global->LDS, 16B/lane, dest = wave-uniform base + lane*16
    __builtin_amdgcn_global_load_lds((__attribute__((address_space(1))) void*)(void*)g,
                                     (__attribute__((address_space(3))) void*)l,
                                     16, 0, 0);
}

// ---- kernel 1: L2 normalize rows, write bf16 matrix + sq (=sum x^2 after norm) ----
__global__ __launch_bounds__(256) void k_normalize(const float* __restrict__ feats,
                                                   unsigned short* __restrict__ xb,
                                                   float* __restrict__ sq) {
    const int row = blockIdx.x;
    const int t = threadIdx.x;
    const float* f = feats + (size_t)row * NDIM + t * 8;
    float4 v0 = *(const float4*)(f);
    float4 v1 = *(const float4*)(f + 4);
    float ss = v0.x*v0.x + v0.y*v0.y + v0.z*v0.z + v0.w*v0.w
             + v1.x*v1.x + v1.y*v1.y + v1.z*v1.z + v1.w*v1.w;
#pragma unroll
    for (int o = 32; o > 0; o >>= 1) ss += __shfl_down(ss, o);
    __shared__ float red[4];
    __shared__ float s_inv;
    if ((t & 63) == 0) red[t >> 6] = ss;
    __syncthreads();
    if (t == 0) {
        float tot = red[0] + red[1] + red[2] + red[3];
        float m = fmaxf(sqrtf(tot), 1e-12f);
        float inv = 1.0f / m;
        sq[row] = tot * inv * inv;
        s_inv = inv;
    }
    __syncthreads();
    float inv = s_inv;
    float vv[8] = {v0.x, v0.y, v0.z, v0.w, v1.x, v1.y, v1.z, v1.w};
    ushortx8 u;
#pragma unroll
    for (int e = 0; e < 8; ++e) u[e] = f2bf(vv[e] * inv);
    *(ushortx8*)(xb + (size_t)row * NDIM + t * 8) = u;
}

// ---- kernel 2: fused bf16 MFMA GEMM (x x^T) + dist + masked running top-5 ----
// grid: 1024 blocks; strip = bx>>4 (row strip of 128), crange = bx&15 (512 cols)
// LDS: As/Bs (16 KB, K-loop) unioned with Dt (34.8 KB, epilogue+scan) = 36 KB
// -> 4 blocks/CU; grid sized to 4 blocks/CU (1024 = 256 CU x 4).
__global__ __launch_bounds__(256, 4) void k_gemm_topk(
        const unsigned short* __restrict__ xb, const float* __restrict__ sq,
        const int* __restrict__ labels, const int* __restrict__ camids,
        float* __restrict__ pos_part, float* __restrict__ neg_part) {
    __shared__ __align__(16) char smem[BM * DT_LD * 2 + 2 * BM * 4 + 2 * BM * 4];
    unsigned short* As = (unsigned short*)smem;            // [0, 8192)
    unsigned short* Bs = (unsigned short*)(smem + BM * BK * 2); // [8192, 16384)
    _Float16* Dt = (_Float16*)smem;                        // [0, 34816)  (aliases As/Bs)
    float* sqr_s = (float*)(smem + BM * DT_LD * 2);        // +512
    float* sqc_s = sqr_s + BM;                             // +512
    int* labcam_r = (int*)(sqc_s + BN);                    // +512 (label<<4 | cam)
    int* labcam_c = labcam_r + BM;                         // +512

    const int tid = threadIdx.x;
    const int w = tid >> 6, lane = tid & 63;
    const int wm = w >> 1, wn = w & 1;
    const int strip = blockIdx.x >> 4;
    const int crange = blockIdx.x & 15;
    const int r0 = strip * BM;
    const int cb0 = crange * (BN * CT);

    if (tid < BM) {
        int gi = r0 + tid;
        sqr_s[tid] = sq[gi];
        labcam_r[tid] = (labels[gi] << 4) | camids[gi];
    }
    __syncthreads();

    const int srow = tid >> 1;       // scan: 2 threads per row
    const int shalf = tid & 1;
    const int pli = labcam_r[srow];

    const float NINF = -__builtin_inff();
    const float PINF =  __builtin_inff();
    float pos5[5] = {NINF, NINF, NINF, NINF, NINF};
    float neg5[5] = {PINF, PINF, PINF, PINF, PINF};

    const int lr = lane >> 2;        // staging: lane -> row within 16-row chunk
    const int lc = (lane & 3) * 8;   // staging: lane -> k offset (8 bf16 = 16B)
    const int m16 = lane & 15;
    const int quad = lane >> 4;

    for (int ct = 0; ct < CT; ++ct) {
        const int cb = cb0 + ct * BN;
        if (tid < BN) {              // safe: previous scan ended with barrier
            int gj = cb + tid;
            sqc_s[tid] = sq[gj];
            labcam_c[tid] = (labels[gj] << 4) | camids[gj];
        }
        floatx4 acc[4][4];
#pragma unroll
        for (int mi = 0; mi < 4; ++mi)
#pragma unroll
            for (int ni = 0; ni < 4; ++ni) {
                floatx4 z = {0.f, 0.f, 0.f, 0.f};
                acc[mi][ni] = z;
            }

        for (int kk = 0; kk < NDIM; kk += BK) {
            __syncthreads();         // previous tile's LDS consumers done
#pragma unroll
            for (int q = 0; q < 2; ++q) {
                const int ra = q * 64 + w * 16;   // wave-uniform chunk base
                load_lds16(xb + (size_t)(r0 + ra + lr) * NDIM + kk + lc, As + ra * BK);
                load_lds16(xb + (size_t)(cb + ra + lr) * NDIM + kk + lc, Bs + ra * BK);
            }
            __syncthreads();         // drains vmcnt(0): data in LDS
            bf16x8 af[4], bfr[4];
#pragma unroll
            for (int mi = 0; mi < 4; ++mi)
                af[mi] = *(const bf16x8*)(As + (wm * 64 + mi * 16 + m16) * BK + quad * 8);
#pragma unroll
            for (int ni = 0; ni < 4; ++ni)
                bfr[ni] = *(const bf16x8*)(Bs + (wn * 64 + ni * 16 + m16) * BK + quad * 8);
#pragma unroll
            for (int mi = 0; mi < 4; ++mi)
#pragma unroll
                for (int ni = 0; ni < 4; ++ni)
                    acc[mi][ni] = __builtin_amdgcn_mfma_f32_16x16x32_bf16(af[mi], bfr[ni], acc[mi][ni], 0, 0, 0);
        }
        __syncthreads();             // all ds_reads of As/Bs done before Dt overwrite

        // epilogue: dot -> dist (fp16) into Dt.  C layout: col=lane&15, row=quad*4+reg
#pragma unroll
        for (int mi = 0; mi < 4; ++mi) {
            const int il = wm * 64 + mi * 16 + quad * 4;
#pragma unroll
            for (int ni = 0; ni < 4; ++ni) {
                const int jl = wn * 64 + ni * 16 + m16;
                const float sj = sqc_s[jl];
#pragma unroll
                for (int r = 0; r < 4; ++r) {
                    float d2 = sqr_s[il + r] + sj - 2.0f * acc[mi][ni][r];
                    Dt[(il + r) * DT_LD + jl] = (_Float16)__builtin_amdgcn_sqrtf(fmaxf(d2, 1e-12f));
                }
            }
        }
        __syncthreads();

        // scan: thread (srow, shalf) scans 64 cols, updates running top-5s
        const int jb = shalf * 64;
#pragma unroll
        for (int c8 = 0; c8 < 8; ++c8) {
            halfx8 v = *(const halfx8*)(Dt + srow * DT_LD + jb + c8 * 8);
            int4 lc0 = *(const int4*)(labcam_c + jb + c8 * 8);
            int4 lc1 = *(const int4*)(labcam_c + jb + c8 * 8 + 4);
            int lcv[8] = {lc0.x, lc0.y, lc0.z, lc0.w, lc1.x, lc1.y, lc1.z, lc1.w};
#pragma unroll
            for (int e = 0; e < 8; ++e) {
                float dist = (float)v[e];
                int x = pli ^ lcv[e];
                bool same_label = (x & ~15) == 0;
                bool same_cam   = (x & 15) == 0;
                if (same_label) {
                    // positive: same label, cross-cam (i==j auto-excluded: same cam)
                    if (!same_cam && dist > pos5[4]) ins_desc(pos5, dist);
                } else {
                    // negative: different label (i==j auto-excluded: same label)
                    float vn = same_cam ? dist * (1.0f / 1.2f) : dist;
                    if (vn < neg5[4]) ins_asc(neg5, vn);
                }
            }
        }
        __syncthreads();
    }

    // merge the two half-row lists: shalf 0<->1 are adjacent lanes in one wave
#pragma unroll
    for (int k = 0; k < 5; ++k) {
        float pv = __shfl_xor(pos5[k], 1);
        float nv = __shfl_xor(neg5[k], 1);
        if (pv > pos5[4]) ins_desc(pos5, pv);
        if (nv < neg5[4]) ins_asc(neg5, nv);
    }
    if (shalf == 0) {
        const int gi = r0 + srow;
        float* pp = pos_part + ((size_t)gi * KLISTS + crange) * 5;
        float* np = neg_part + ((size_t)gi * KLISTS + crange) * 5;
#pragma unroll
        for (int k = 0; k < 5; ++k) { pp[k] = pos5[k]; np[k] = neg5[k]; }
    }
}

// ---- kernel 3: merge 16 partial lists/row -> d_ap, d_an, w0, per_sample; block partials ----
__global__ __launch_bounds__(256) void k_merge(const float* __restrict__ pos_part,
        const float* __restrict__ neg_part, const int* __restrict__ epoch_p,
        float* __restrict__ out, float* __restrict__ wsum_p, float* __restrict__ wpsum_p) {
    const int row = blockIdx.x * 256 + threadIdx.x;
    const float NINF = -__builtin_inff(), PINF = __builtin_inff();
    float p5[5] = {NINF, NINF, NINF, NINF, NINF};
    float n5[5] = {PINF, PINF, PINF, PINF, PINF};
    const float* pp = pos_part + (size_t)row * (KLISTS * 5);
    const float* np = neg_part + (size_t)row * (KLISTS * 5);
    for (int k = 0; k < KLISTS * 5; ++k) {
        float v = pp[k];
        if (v > p5[4]) ins_desc(p5, v);
    }
    for (int k = 0; k < KLISTS * 5; ++k) {
        float v = np[k];
        if (v < n5[4]) ins_asc(n5, v);
    }
    float s = 0.f; int c = 0;
#pragma unroll
    for (int k = 0; k < 5; ++k) { bool fin = (p5[k] > NINF); s += fin ? p5[k] : 0.f; c += fin ? 1 : 0; }
    float d_ap = (c > 0) ? s / (float)c : NINF;          // fallback = max(work) = -inf
    s = 0.f; c = 0;
#pragma unroll
    for (int k = 0; k < 5; ++k) { bool fin = (n5[k] < PINF); s += fin ? n5[k] : 0.f; c += fin ? 1 : 0; }
    float d_an = (c > 0) ? s / (float)c : PINF;          // fallback = min(work) = +inf

    out[1 + row] = d_ap;
    out[1 + NROW + row] = d_an;

    float diff = d_ap - d_an;                            // never NaN (d_ap!=+inf, d_an!=-inf)
    float w0 = 1.0f / (1.0f + expf(-2.0f * diff));       // sigmoid(ALPHA*(d_ap-d_an))
    float p;
    if (*epoch_p < 10) {
        p = fmaxf(diff, 0.0f) + log1pf(expf(-fabsf(diff)));  // stable softplus(diff)
    } else {
        p = fmaxf(diff + 0.3f, 0.0f);                    // relu(d_ap - d_an + MARGIN)
    }
    float wp = w0 * p;
#pragma unroll
    for (int o = 32; o > 0; o >>= 1) { w0 += __shfl_down(w0, o); wp += __shfl_down(wp, o); }
    __shared__ float rw[4], rp[4];
    const int t = threadIdx.x;
    if ((t & 63) == 0) { rw[t >> 6] = w0; rp[t >> 6] = wp; }
    __syncthreads();
    if (t == 0) {
        wsum_p[blockIdx.x]  = rw[0] + rw[1] + rw[2] + rw[3];
        wpsum_p[blockIdx.x] = rp[0] + rp[1] + rp[2] + rp[3];
    }
}

// ---- kernel 4: finalize loss scalar ----
__global__ void k_finalize(const float* __restrict__ wsum_p, const float* __restrict__ wpsum_p,
                           float* __restrict__ out) {
    if (threadIdx.x == 0) {
        float sw = 0.f, swp = 0.f;
        for (int i = 0; i < 32; ++i) { sw += wsum_p[i]; swp += wpsum_p[i]; }
        float M = fmaxf(sw / (float)NROW, 1e-12f);
        out[0] = swp / ((float)NROW * M);
    }
}

extern "C" void kernel_launch(void* const* d_in, const int* in_sizes, int n_in,
                              void* d_out, int out_size, void* d_ws, size_t ws_size,
                              hipStream_t stream) {
    const float* feats  = (const float*)d_in[0];
    const int*   labels = (const int*)d_in[1];
    const int*   camids = (const int*)d_in[2];
    const int*   epoch  = (const int*)d_in[3];
    float* out = (float*)d_out;
    char* ws = (char*)d_ws;
    // workspace layout (~38.8 MB total)
    unsigned short* xb = (unsigned short*)ws;                              // 33,554,432 B
    float* sq        = (float*)(ws + 33554432);                            //     32,768 B
    float* pos_part  = (float*)(ws + 33554432 + 32768);                    //  2,621,440 B
    float* neg_part  = (float*)(ws + 33554432 + 32768 + 2621440);          //  2,621,440 B
    float* wsum_p    = (float*)(ws + 33554432 + 32768 + 2u * 2621440);     //        128 B
    float* wpsum_p   = wsum_p + 32;                                        //        128 B

    k_normalize<<<NROW, 256, 0, stream>>>(feats, xb, sq);
    k_gemm_topk<<<64 * NCR, 256, 0, stream>>>(xb, sq, labels, camids, pos_part, neg_part);
    k_merge<<<NROW / 256, 256, 0, stream>>>(pos_part, neg_part, epoch, out, wsum_p, wpsum_p);
    k_finalize<<<1, 64, 0, stream>>>(wsum_p, wpsum_p, out);
}

// Round 4
// 365.647 us; speedup vs baseline: 1.5865x; 1.3277x over previous
//
#include <hip/hip_runtime.h>
#include <hip/hip_bf16.h>
#include <stdint.h>

// ---- types ----
typedef float   floatx4  __attribute__((ext_vector_type(4)));
typedef __bf16  bf16x8   __attribute__((ext_vector_type(8)));
typedef _Float16 halfx8  __attribute__((ext_vector_type(8)));
typedef _Float16 halfx4  __attribute__((ext_vector_type(4)));
typedef unsigned short ushortx8 __attribute__((ext_vector_type(8)));

#define NROW 8192
#define NDIM 2048
#define BM 128
#define BN 128
#define BK 32
#define NSTRIP 64                       // NROW/BM
#define NTILE (NSTRIP*(NSTRIP+1)/2)     // 2080 triangle tiles
#define DT_LD 136       // Dt row stride in halves (272 B: 16B-aligned b128 reads)
#define KL_SYM 64       // sym path: one 5-list per row per other-strip
// fallback (R3) path constants
#define CT 4
#define NCR 16
#define KLISTS 16

__device__ __forceinline__ unsigned short f2bf(float f) {
    union { float f; unsigned u; } x; x.f = f;
    unsigned r = x.u + 0x7fffu + ((x.u >> 16) & 1u);   // RNE
    return (unsigned short)(r >> 16);
}

// insert v into descending-sorted a[5] (keeps 5 largest)
__device__ __forceinline__ void ins_desc(float (&a)[5], float v) {
#pragma unroll
    for (int k = 0; k < 5; ++k) { float hi = fmaxf(a[k], v); float lo = fminf(a[k], v); a[k] = hi; v = lo; }
}
// insert v into ascending-sorted a[5] (keeps 5 smallest)
__device__ __forceinline__ void ins_asc(float (&a)[5], float v) {
#pragma unroll
    for (int k = 0; k < 5; ++k) { float lo = fminf(a[k], v); float hi = fmaxf(a[k], v); a[k] = lo; v = hi; }
}

__device__ __forceinline__ void load_lds16(const void* g, void* l) {
    // async global->LDS, 16B/lane, dest = wave-uniform base + lane*16
    __builtin_amdgcn_global_load_lds((__attribute__((address_space(1))) void*)(void*)g,
                                     (__attribute__((address_space(3))) void*)l,
                                     16, 0, 0);
}

// ---- kernel 1: L2 normalize rows, write bf16 matrix + sq (=sum x^2 after norm) ----
__global__ __launch_bounds__(256) void k_normalize(const float* __restrict__ feats,
                                                   unsigned short* __restrict__ xb,
                                                   float* __restrict__ sq) {
    const int row = blockIdx.x;
    const int t = threadIdx.x;
    const float* f = feats + (size_t)row * NDIM + t * 8;
    float4 v0 = *(const float4*)(f);
    float4 v1 = *(const float4*)(f + 4);
    float ss = v0.x*v0.x + v0.y*v0.y + v0.z*v0.z + v0.w*v0.w
             + v1.x*v1.x + v1.y*v1.y + v1.z*v1.z + v1.w*v1.w;
#pragma unroll
    for (int o = 32; o > 0; o >>= 1) ss += __shfl_down(ss, o);
    __shared__ float red[4];
    __shared__ float s_inv;
    if ((t & 63) == 0) red[t >> 6] = ss;
    __syncthreads();
    if (t == 0) {
        float tot = red[0] + red[1] + red[2] + red[3];
        float m = fmaxf(sqrtf(tot), 1e-12f);
        float inv = 1.0f / m;
        sq[row] = tot * inv * inv;
        s_inv = inv;
    }
    __syncthreads();
    float inv = s_inv;
    float vv[8] = {v0.x, v0.y, v0.z, v0.w, v1.x, v1.y, v1.z, v1.w};
    ushortx8 u;
#pragma unroll
    for (int e = 0; e < 8; ++e) u[e] = f2bf(vv[e] * inv);
    *(ushortx8*)(xb + (size_t)row * NDIM + t * 8) = u;
}

// ---- shared scan helper: half-row scan over 64 cols in d2 domain ----
__device__ __forceinline__ void scan_half_row(const _Float16* Dt_, const int* labcam_cols,
        int srow, int shalf, int pli, float (&pos5)[5], float (&neg5)[5]) {
    const int jb = shalf * 64;
#pragma unroll
    for (int c8 = 0; c8 < 8; ++c8) {
        halfx8 v = *(const halfx8*)(Dt_ + srow * DT_LD + jb + c8 * 8);
        int4 lc0 = *(const int4*)(labcam_cols + jb + c8 * 8);
        int4 lc1 = *(const int4*)(labcam_cols + jb + c8 * 8 + 4);
        int lcv[8] = {lc0.x, lc0.y, lc0.z, lc0.w, lc1.x, lc1.y, lc1.z, lc1.w};
#pragma unroll
        for (int e = 0; e < 8; ++e) {
            float d2 = (float)v[e];
            int x = pli ^ lcv[e];
            bool same_label = (x & ~15) == 0;
            bool same_cam   = (x & 15) == 0;
            if (same_label) {
                // positive: same label, cross-cam (i==j auto-excluded: same cam)
                if (!same_cam && d2 > pos5[4]) ins_desc(pos5, d2);
            } else {
                // negative: diff label; same-cam boost dist/1.2 == d2/1.44 (monotone)
                float vn = same_cam ? d2 * (1.0f / 1.44f) : d2;
                if (vn < neg5[4]) ins_asc(neg5, vn);
            }
        }
    }
}

// merge the two half-row lists (adjacent lanes) and write fp16 5-lists
__device__ __forceinline__ void emit_lists(float (&pos5)[5], float (&neg5)[5], int shalf,
        _Float16* posp, _Float16* negp, size_t gi, int slot) {
#pragma unroll
    for (int k = 0; k < 5; ++k) {
        float pv = __shfl_xor(pos5[k], 1);
        float nv = __shfl_xor(neg5[k], 1);
        if (pv > pos5[4]) ins_desc(pos5, pv);
        if (nv < neg5[4]) ins_asc(neg5, nv);
    }
    if (shalf == 0) {
        _Float16* pp = posp + (gi * KL_SYM + slot) * 5;
        _Float16* np = negp + (gi * KL_SYM + slot) * 5;
#pragma unroll
        for (int k = 0; k < 5; ++k) { pp[k] = (_Float16)pos5[k]; np[k] = (_Float16)neg5[k]; }
    }
}

// ---- kernel 2 (sym): one block per triangle tile (a,b), b<=a.  dist symmetric:
// pass 1 scans rows of strip a (row-major Dt); pass 2 (a!=b) rewrites Dt
// transposed from live accs and scans rows of strip b.  d2 stored; sqrt deferred.
__global__ __launch_bounds__(256, 4) void k_gemm_sym(
        const unsigned short* __restrict__ xb, const float* __restrict__ sq,
        const int* __restrict__ labels, const int* __restrict__ camids,
        _Float16* __restrict__ posp, _Float16* __restrict__ negp) {
    __shared__ __align__(16) char smem[BM * DT_LD * 2 + 4 * BM * 4];
    unsigned short* As = (unsigned short*)smem;                 // [0, 8192)
    unsigned short* Bs = (unsigned short*)(smem + BM * BK * 2); // [8192, 16384)
    _Float16* Dt = (_Float16*)smem;                             // [0, 34816) aliases As/Bs
    float* sqr_s = (float*)(smem + BM * DT_LD * 2);
    float* sqc_s = sqr_s + BM;
    int* labcam_a = (int*)(sqc_s + BM);
    int* labcam_b = labcam_a + BM;

    const int tid = threadIdx.x;
    const int w = tid >> 6, lane = tid & 63;
    const int wm = w >> 1, wn = w & 1;

    // triangle decode: bx -> (a,b), b<=a
    int bx = blockIdx.x;
    int a = (int)((sqrtf(8.0f * (float)bx + 1.0f) - 1.0f) * 0.5f);
    while ((a + 1) * (a + 2) / 2 <= bx) ++a;
    while (a * (a + 1) / 2 > bx) --a;
    const int b = bx - a * (a + 1) / 2;
    const int r0 = a * BM, c0 = b * BM;

    if (tid < BM) {
        int gi = r0 + tid;
        sqr_s[tid] = sq[gi];
        labcam_a[tid] = (labels[gi] << 4) | camids[gi];
    } else {
        int t2 = tid - BM;
        int gj = c0 + t2;
        sqc_s[t2] = sq[gj];
        labcam_b[t2] = (labels[gj] << 4) | camids[gj];
    }
    __syncthreads();

    const int srow = tid >> 1;       // scan: 2 threads per row
    const int shalf = tid & 1;

    const int lr = lane >> 2;        // staging: lane -> row within 16-row chunk
    const int lc = (lane & 3) * 8;   // staging: lane -> k offset (8 bf16 = 16B)
    const int m16 = lane & 15;
    const int quad = lane >> 4;

    floatx4 acc[4][4];
#pragma unroll
    for (int mi = 0; mi < 4; ++mi)
#pragma unroll
        for (int ni = 0; ni < 4; ++ni) {
            floatx4 z = {0.f, 0.f, 0.f, 0.f};
            acc[mi][ni] = z;
        }

    for (int kk = 0; kk < NDIM; kk += BK) {
        __syncthreads();             // previous iter's LDS consumers done
#pragma unroll
        for (int q = 0; q < 2; ++q) {
            const int ra = q * 64 + w * 16;   // wave-uniform chunk base
            load_lds16(xb + (size_t)(r0 + ra + lr) * NDIM + kk + lc, As + ra * BK);
            load_lds16(xb + (size_t)(c0 + ra + lr) * NDIM + kk + lc, Bs + ra * BK);
        }
        __syncthreads();             // drains vmcnt(0): data in LDS
        bf16x8 af[4], bfr[4];
#pragma unroll
        for (int mi = 0; mi < 4; ++mi)
            af[mi] = *(const bf16x8*)(As + (wm * 64 + mi * 16 + m16) * BK + quad * 8);
#pragma unroll
        for (int ni = 0; ni < 4; ++ni)
            bfr[ni] = *(const bf16x8*)(Bs + (wn * 64 + ni * 16 + m16) * BK + quad * 8);
#pragma unroll
        for (int mi = 0; mi < 4; ++mi)
#pragma unroll
            for (int ni = 0; ni < 4; ++ni)
                acc[mi][ni] = __builtin_amdgcn_mfma_f32_16x16x32_bf16(af[mi], bfr[ni], acc[mi][ni], 0, 0, 0);
    }
    __syncthreads();                 // all ds_reads of As/Bs done before Dt overwrite

    // ---- pass 1: d2 row-major; scan rows of strip a over cols of strip b ----
#pragma unroll
    for (int mi = 0; mi < 4; ++mi) {
        const int il = wm * 64 + mi * 16 + quad * 4;
#pragma unroll
        for (int ni = 0; ni < 4; ++ni) {
            const int jl = wn * 64 + ni * 16 + m16;
            const float sj = sqc_s[jl];
#pragma unroll
            for (int r = 0; r < 4; ++r) {
                float d2 = fmaxf(sqr_s[il + r] + sj - 2.0f * acc[mi][ni][r], 1e-12f);
                Dt[(il + r) * DT_LD + jl] = (_Float16)d2;
            }
        }
    }
    __syncthreads();

    const float NINF = -__builtin_inff();
    const float PINF =  __builtin_inff();
    float pos5[5] = {NINF, NINF, NINF, NINF, NINF};
    float neg5[5] = {PINF, PINF, PINF, PINF, PINF};
    scan_half_row(Dt, labcam_b, srow, shalf, labcam_a[srow], pos5, neg5);
    emit_lists(pos5, neg5, shalf, posp, negp, (size_t)(r0 + srow), b);

    if (a != b) {
        __syncthreads();             // pass-1 scan reads done before Dt overwrite
        // ---- pass 2: d2 transposed (b64 packed writes); scan rows of strip b ----
#pragma unroll
        for (int ni = 0; ni < 4; ++ni) {
            const int jl = wn * 64 + ni * 16 + m16;
            const float sj = sqc_s[jl];
#pragma unroll
            for (int mi = 0; mi < 4; ++mi) {
                const int il = wm * 64 + mi * 16 + quad * 4;
                halfx4 h;
#pragma unroll
                for (int r = 0; r < 4; ++r)
                    h[r] = (_Float16)fmaxf(sqr_s[il + r] + sj - 2.0f * acc[mi][ni][r], 1e-12f);
                *(halfx4*)(Dt + jl * DT_LD + il) = h;
            }
        }
        __syncthreads();
#pragma unroll
        for (int k = 0; k < 5; ++k) { pos5[k] = NINF; neg5[k] = PINF; }
        scan_half_row(Dt, labcam_a, srow, shalf, labcam_b[srow], pos5, neg5);
        emit_lists(pos5, neg5, shalf, posp, negp, (size_t)(c0 + srow), a);
    }
}

// ---- kernel 3 (sym): merge 64 fp16 d2-lists/row -> d_ap, d_an, weights ----
__global__ __launch_bounds__(256) void k_merge_sym(const _Float16* __restrict__ posp,
        const _Float16* __restrict__ negp, const int* __restrict__ epoch_p,
        float* __restrict__ out, float* __restrict__ wsum_p, float* __restrict__ wpsum_p) {
    const int row = blockIdx.x * 256 + threadIdx.x;
    const float NINF = -__builtin_inff(), PINF = __builtin_inff();
    float p5[5] = {NINF, NINF, NINF, NINF, NINF};
    float n5[5] = {PINF, PINF, PINF, PINF, PINF};
    const halfx8* pv8 = (const halfx8*)(posp + (size_t)row * (KL_SYM * 5));
    const halfx8* nv8 = (const halfx8*)(negp + (size_t)row * (KL_SYM * 5));
    for (int k = 0; k < KL_SYM * 5 / 8; ++k) {
        halfx8 v = pv8[k];
#pragma unroll
        for (int e = 0; e < 8; ++e) { float f = (float)v[e]; if (f > p5[4]) ins_desc(p5, f); }
    }
    for (int k = 0; k < KL_SYM * 5 / 8; ++k) {
        halfx8 v = nv8[k];
#pragma unroll
        for (int e = 0; e < 8; ++e) { float f = (float)v[e]; if (f < n5[4]) ins_asc(n5, f); }
    }
    // d2 -> dist on the 5 survivors only
    float s = 0.f; int c = 0;
#pragma unroll
    for (int k = 0; k < 5; ++k) { bool fin = (p5[k] > NINF); s += fin ? sqrtf(p5[k]) : 0.f; c += fin ? 1 : 0; }
    float d_ap = (c > 0) ? s / (float)c : NINF;
    s = 0.f; c = 0;
#pragma unroll
    for (int k = 0; k < 5; ++k) { bool fin = (n5[k] < PINF); s += fin ? sqrtf(n5[k]) : 0.f; c += fin ? 1 : 0; }
    float d_an = (c > 0) ? s / (float)c : PINF;

    out[1 + row] = d_ap;
    out[1 + NROW + row] = d_an;

    float diff = d_ap - d_an;
    float w0 = 1.0f / (1.0f + expf(-2.0f * diff));       // sigmoid(ALPHA*(d_ap-d_an))
    float p;
    if (*epoch_p < 10) {
        p = fmaxf(diff, 0.0f) + log1pf(expf(-fabsf(diff)));  // stable softplus(diff)
    } else {
        p = fmaxf(diff + 0.3f, 0.0f);                    // relu(d_ap - d_an + MARGIN)
    }
    float wp = w0 * p;
#pragma unroll
    for (int o = 32; o > 0; o >>= 1) { w0 += __shfl_down(w0, o); wp += __shfl_down(wp, o); }
    __shared__ float rw[4], rp[4];
    const int t = threadIdx.x;
    if ((t & 63) == 0) { rw[t >> 6] = w0; rp[t >> 6] = wp; }
    __syncthreads();
    if (t == 0) {
        wsum_p[blockIdx.x]  = rw[0] + rw[1] + rw[2] + rw[3];
        wpsum_p[blockIdx.x] = rp[0] + rp[1] + rp[2] + rp[3];
    }
}

// ================== fallback (R3) path, byte-identical logic ==================
__global__ __launch_bounds__(256, 4) void k_gemm_topk(
        const unsigned short* __restrict__ xb, const float* __restrict__ sq,
        const int* __restrict__ labels, const int* __restrict__ camids,
        float* __restrict__ pos_part, float* __restrict__ neg_part) {
    __shared__ __align__(16) char smem[BM * DT_LD * 2 + 2 * BM * 4 + 2 * BM * 4];
    unsigned short* As = (unsigned short*)smem;
    unsigned short* Bs = (unsigned short*)(smem + BM * BK * 2);
    _Float16* Dt = (_Float16*)smem;
    float* sqr_s = (float*)(smem + BM * DT_LD * 2);
    float* sqc_s = sqr_s + BM;
    int* labcam_r = (int*)(sqc_s + BN);
    int* labcam_c = labcam_r + BM;

    const int tid = threadIdx.x;
    const int w = tid >> 6, lane = tid & 63;
    const int wm = w >> 1, wn = w & 1;
    const int strip = blockIdx.x >> 4;
    const int crange = blockIdx.x & 15;
    const int r0 = strip * BM;
    const int cb0 = crange * (BN * CT);

    if (tid < BM) {
        int gi = r0 + tid;
        sqr_s[tid] = sq[gi];
        labcam_r[tid] = (labels[gi] << 4) | camids[gi];
    }
    __syncthreads();

    const int srow = tid >> 1;
    const int shalf = tid & 1;
    const int pli = labcam_r[srow];

    const float NINF = -__builtin_inff();
    const float PINF =  __builtin_inff();
    float pos5[5] = {NINF, NINF, NINF, NINF, NINF};
    float neg5[5] = {PINF, PINF, PINF, PINF, PINF};

    const int lr = lane >> 2;
    const int lc = (lane & 3) * 8;
    const int m16 = lane & 15;
    const int quad = lane >> 4;

    for (int ct = 0; ct < CT; ++ct) {
        const int cb = cb0 + ct * BN;
        if (tid < BN) {
            int gj = cb + tid;
            sqc_s[tid] = sq[gj];
            labcam_c[tid] = (labels[gj] << 4) | camids[gj];
        }
        floatx4 acc[4][4];
#pragma unroll
        for (int mi = 0; mi < 4; ++mi)
#pragma unroll
            for (int ni = 0; ni < 4; ++ni) {
                floatx4 z = {0.f, 0.f, 0.f, 0.f};
                acc[mi][ni] = z;
            }

        for (int kk = 0; kk < NDIM; kk += BK) {
            __syncthreads();
#pragma unroll
            for (int q = 0; q < 2; ++q) {
                const int ra = q * 64 + w * 16;
                load_lds16(xb + (size_t)(r0 + ra + lr) * NDIM + kk + lc, As + ra * BK);
                load_lds16(xb + (size_t)(cb + ra + lr) * NDIM + kk + lc, Bs + ra * BK);
            }
            __syncthreads();
            bf16x8 af[4], bfr[4];
#pragma unroll
            for (int mi = 0; mi < 4; ++mi)
                af[mi] = *(const bf16x8*)(As + (wm * 64 + mi * 16 + m16) * BK + quad * 8);
#pragma unroll
            for (int ni = 0; ni < 4; ++ni)
                bfr[ni] = *(const bf16x8*)(Bs + (wn * 64 + ni * 16 + m16) * BK + quad * 8);
#pragma unroll
            for (int mi = 0; mi < 4; ++mi)
#pragma unroll
                for (int ni = 0; ni < 4; ++ni)
                    acc[mi][ni] = __builtin_amdgcn_mfma_f32_16x16x32_bf16(af[mi], bfr[ni], acc[mi][ni], 0, 0, 0);
        }
        __syncthreads();

#pragma unroll
        for (int mi = 0; mi < 4; ++mi) {
            const int il = wm * 64 + mi * 16 + quad * 4;
#pragma unroll
            for (int ni = 0; ni < 4; ++ni) {
                const int jl = wn * 64 + ni * 16 + m16;
                const float sj = sqc_s[jl];
#pragma unroll
                for (int r = 0; r < 4; ++r) {
                    float d2 = sqr_s[il + r] + sj - 2.0f * acc[mi][ni][r];
                    Dt[(il + r) * DT_LD + jl] = (_Float16)__builtin_amdgcn_sqrtf(fmaxf(d2, 1e-12f));
                }
            }
        }
        __syncthreads();

        const int jb = shalf * 64;
#pragma unroll
        for (int c8 = 0; c8 < 8; ++c8) {
            halfx8 v = *(const halfx8*)(Dt + srow * DT_LD + jb + c8 * 8);
            int4 lc0 = *(const int4*)(labcam_c + jb + c8 * 8);
            int4 lc1 = *(const int4*)(labcam_c + jb + c8 * 8 + 4);
            int lcv[8] = {lc0.x, lc0.y, lc0.z, lc0.w, lc1.x, lc1.y, lc1.z, lc1.w};
#pragma unroll
            for (int e = 0; e < 8; ++e) {
                float dist = (float)v[e];
                int x = pli ^ lcv[e];
                bool same_label = (x & ~15) == 0;
                bool same_cam   = (x & 15) == 0;
                if (same_label) {
                    if (!same_cam && dist > pos5[4]) ins_desc(pos5, dist);
                } else {
                    float vn = same_cam ? dist * (1.0f / 1.2f) : dist;
                    if (vn < neg5[4]) ins_asc(neg5, vn);
                }
            }
        }
        __syncthreads();
    }

#pragma unroll
    for (int k = 0; k < 5; ++k) {
        float pv = __shfl_xor(pos5[k], 1);
        float nv = __shfl_xor(neg5[k], 1);
        if (pv > pos5[4]) ins_desc(pos5, pv);
        if (nv < neg5[4]) ins_asc(neg5, nv);
    }
    if (shalf == 0) {
        const int gi = r0 + srow;
        float* pp = pos_part + ((size_t)gi * KLISTS + crange) * 5;
        float* np = neg_part + ((size_t)gi * KLISTS + crange) * 5;
#pragma unroll
        for (int k = 0; k < 5; ++k) { pp[k] = pos5[k]; np[k] = neg5[k]; }
    }
}

__global__ __launch_bounds__(256) void k_merge(const float* __restrict__ pos_part,
        const float* __restrict__ neg_part, const int* __restrict__ epoch_p,
        float* __restrict__ out, float* __restrict__ wsum_p, float* __restrict__ wpsum_p) {
    const int row = blockIdx.x * 256 + threadIdx.x;
    const float NINF = -__builtin_inff(), PINF = __builtin_inff();
    float p5[5] = {NINF, NINF, NINF, NINF, NINF};
    float n5[5] = {PINF, PINF, PINF, PINF, PINF};
    const float* pp = pos_part + (size_t)row * (KLISTS * 5);
    const float* np = neg_part + (size_t)row * (KLISTS * 5);
    for (int k = 0; k < KLISTS * 5; ++k) {
        float v = pp[k];
        if (v > p5[4]) ins_desc(p5, v);
    }
    for (int k = 0; k < KLISTS * 5; ++k) {
        float v = np[k];
        if (v < n5[4]) ins_asc(n5, v);
    }
    float s = 0.f; int c = 0;
#pragma unroll
    for (int k = 0; k < 5; ++k) { bool fin = (p5[k] > NINF); s += fin ? p5[k] : 0.f; c += fin ? 1 : 0; }
    float d_ap = (c > 0) ? s / (float)c : NINF;
    s = 0.f; c = 0;
#pragma unroll
    for (int k = 0; k < 5; ++k) { bool fin = (n5[k] < PINF); s += fin ? n5[k] : 0.f; c += fin ? 1 : 0; }
    float d_an = (c > 0) ? s / (float)c : PINF;

    out[1 + row] = d_ap;
    out[1 + NROW + row] = d_an;

    float diff = d_ap - d_an;
    float w0 = 1.0f / (1.0f + expf(-2.0f * diff));
    float p;
    if (*epoch_p < 10) {
        p = fmaxf(diff, 0.0f) + log1pf(expf(-fabsf(diff)));
    } else {
        p = fmaxf(diff + 0.3f, 0.0f);
    }
    float wp = w0 * p;
#pragma unroll
    for (int o = 32; o > 0; o >>= 1) { w0 += __shfl_down(w0, o); wp += __shfl_down(wp, o); }
    __shared__ float rw[4], rp[4];
    const int t = threadIdx.x;
    if ((t & 63) == 0) { rw[t >> 6] = w0; rp[t >> 6] = wp; }
    __syncthreads();
    if (t == 0) {
        wsum_p[blockIdx.x]  = rw[0] + rw[1] + rw[2] + rw[3];
        wpsum_p[blockIdx.x] = rp[0] + rp[1] + rp[2] + rp[3];
    }
}

// ---- kernel 4: finalize loss scalar ----
__global__ void k_finalize(const float* __restrict__ wsum_p, const float* __restrict__ wpsum_p,
                           float* __restrict__ out) {
    if (threadIdx.x == 0) {
        float sw = 0.f, swp = 0.f;
        for (int i = 0; i < 32; ++i) { sw += wsum_p[i]; swp += wpsum_p[i]; }
        float M = fmaxf(sw / (float)NROW, 1e-12f);
        out[0] = swp / ((float)NROW * M);
    }
}

extern "C" void kernel_launch(void* const* d_in, const int* in_sizes, int n_in,
                              void* d_out, int out_size, void* d_ws, size_t ws_size,
                              hipStream_t stream) {
    const float* feats  = (const float*)d_in[0];
    const int*   labels = (const int*)d_in[1];
    const int*   camids = (const int*)d_in[2];
    const int*   epoch  = (const int*)d_in[3];
    float* out = (float*)d_out;
    char* ws = (char*)d_ws;

    unsigned short* xb = (unsigned short*)ws;                  // 33,554,432 B
    float* sq = (float*)(ws + 33554432);                       //     32,768 B

    const size_t HALF_LIST_BYTES = (size_t)NROW * KL_SYM * 5 * 2;   // 5,242,880
    const size_t SYM_NEED = 33554432ull + 32768 + 2 * HALF_LIST_BYTES + 256;

    k_normalize<<<NROW, 256, 0, stream>>>(feats, xb, sq);

    if (ws_size >= SYM_NEED) {
        // symmetric path (half the GEMM work)
        _Float16* posp = (_Float16*)(ws + 33554432 + 32768);
        _Float16* negp = (_Float16*)(ws + 33554432 + 32768 + HALF_LIST_BYTES);
        float* wsum_p  = (float*)(ws + 33554432 + 32768 + 2 * HALF_LIST_BYTES);
        float* wpsum_p = wsum_p + 32;
        k_gemm_sym<<<NTILE, 256, 0, stream>>>(xb, sq, labels, camids, posp, negp);
        k_merge_sym<<<NROW / 256, 256, 0, stream>>>(posp, negp, epoch, out, wsum_p, wpsum_p);
        k_finalize<<<1, 64, 0, stream>>>(wsum_p, wpsum_p, out);
    } else {
        // fallback: proven R3 path (38.8 MB workspace)
        float* pos_part  = (float*)(ws + 33554432 + 32768);
        float* neg_part  = (float*)(ws + 33554432 + 32768 + 2621440);
        float* wsum_p    = (float*)(ws + 33554432 + 32768 + 2u * 2621440);
        float* wpsum_p   = wsum_p + 32;
        k_gemm_topk<<<64 * NCR, 256, 0, stream>>>(xb, sq, labels, camids, pos_part, neg_part);
        k_merge<<<NROW / 256, 256, 0, stream>>>(pos_part, neg_part, epoch, out, wsum_p, wpsum_p);
        k_finalize<<<1, 64, 0, stream>>>(wsum_p, wpsum_p, out);
    }
}

// Round 5
// 319.522 us; speedup vs baseline: 1.8156x; 1.1444x over previous
//
#include <hip/hip_runtime.h>
#include <hip/hip_bf16.h>
#include <stdint.h>

// ---- types ----
typedef float   floatx4  __attribute__((ext_vector_type(4)));
typedef __bf16  bf16x8   __attribute__((ext_vector_type(8)));
typedef _Float16 halfx8  __attribute__((ext_vector_type(8)));
typedef _Float16 halfx4  __attribute__((ext_vector_type(4)));
typedef unsigned short ushortx8 __attribute__((ext_vector_type(8)));

#define NROW 8192
#define NDIM 2048
#define BM 128
#define BK 64                           // row = 128 B = 8 x 16B chunks (swizzle domain)
#define NSTRIP 64                       // NROW/BM
#define NTILE (NSTRIP*(NSTRIP+1)/2)     // 2080 triangle tiles
#define DT_LD 136       // Dt row stride in halves (272 B; rows 16B-aligned)
#define KL_SYM 64       // one 5-list per row per other-strip

__device__ __forceinline__ unsigned short f2bf(float f) {
    union { float f; unsigned u; } x; x.f = f;
    unsigned r = x.u + 0x7fffu + ((x.u >> 16) & 1u);   // RNE
    return (unsigned short)(r >> 16);
}

// insert v into descending-sorted a[5] (keeps 5 largest)
__device__ __forceinline__ void ins_desc(float (&a)[5], float v) {
#pragma unroll
    for (int k = 0; k < 5; ++k) { float hi = fmaxf(a[k], v); float lo = fminf(a[k], v); a[k] = hi; v = lo; }
}
// insert v into ascending-sorted a[5] (keeps 5 smallest)
__device__ __forceinline__ void ins_asc(float (&a)[5], float v) {
#pragma unroll
    for (int k = 0; k < 5; ++k) { float lo = fminf(a[k], v); float hi = fmaxf(a[k], v); a[k] = lo; v = hi; }
}

__device__ __forceinline__ void load_lds16(const void* g, void* l) {
    // async global->LDS, 16B/lane, dest = wave-uniform base + lane*16
    __builtin_amdgcn_global_load_lds((__attribute__((address_space(1))) void*)(void*)g,
                                     (__attribute__((address_space(3))) void*)l,
                                     16, 0, 0);
}

// ---- kernel 1: L2 normalize rows, write bf16 matrix + sq (=sum x^2 after norm) ----
__global__ __launch_bounds__(256) void k_normalize(const float* __restrict__ feats,
                                                   unsigned short* __restrict__ xb,
                                                   float* __restrict__ sq) {
    const int row = blockIdx.x;
    const int t = threadIdx.x;
    const float* f = feats + (size_t)row * NDIM + t * 8;
    float4 v0 = *(const float4*)(f);
    float4 v1 = *(const float4*)(f + 4);
    float ss = v0.x*v0.x + v0.y*v0.y + v0.z*v0.z + v0.w*v0.w
             + v1.x*v1.x + v1.y*v1.y + v1.z*v1.z + v1.w*v1.w;
#pragma unroll
    for (int o = 32; o > 0; o >>= 1) ss += __shfl_down(ss, o);
    __shared__ float red[4];
    __shared__ float s_inv;
    if ((t & 63) == 0) red[t >> 6] = ss;
    __syncthreads();
    if (t == 0) {
        float tot = red[0] + red[1] + red[2] + red[3];
        float m = fmaxf(sqrtf(tot), 1e-12f);
        float inv = 1.0f / m;
        sq[row] = tot * inv * inv;
        s_inv = inv;
    }
    __syncthreads();
    float inv = s_inv;
    float vv[8] = {v0.x, v0.y, v0.z, v0.w, v1.x, v1.y, v1.z, v1.w};
    ushortx8 u;
#pragma unroll
    for (int e = 0; e < 8; ++e) u[e] = f2bf(vv[e] * inv);
    *(ushortx8*)(xb + (size_t)row * NDIM + t * 8) = u;
}

// ---- scan helper: half-row scan over 64 cols in d2 domain (Dt chunk-swizzled) ----
__device__ __forceinline__ void scan_half_row(const _Float16* Dt_, const int* labcam_cols,
        int srow, int shalf, int pli, float (&pos5)[5], float (&neg5)[5]) {
    const int jb = shalf * 64;
    const int sw = srow & 7;
#pragma unroll
    for (int c8 = 0; c8 < 8; ++c8) {
        // chunk position = logical chunk ^ (row&7); low-3-bit XOR stays within half
        halfx8 v = *(const halfx8*)(Dt_ + srow * DT_LD + ((shalf * 8 + (c8 ^ sw)) << 3));
        int4 lc0 = *(const int4*)(labcam_cols + jb + c8 * 8);
        int4 lc1 = *(const int4*)(labcam_cols + jb + c8 * 8 + 4);
        int lcv[8] = {lc0.x, lc0.y, lc0.z, lc0.w, lc1.x, lc1.y, lc1.z, lc1.w};
#pragma unroll
        for (int e = 0; e < 8; ++e) {
            float d2 = (float)v[e];
            int x = pli ^ lcv[e];
            bool same_label = (x & ~15) == 0;
            bool same_cam   = (x & 15) == 0;
            if (same_label) {
                // positive: same label, cross-cam (i==j auto-excluded: same cam)
                if (!same_cam && d2 > pos5[4]) ins_desc(pos5, d2);
            } else {
                // negative: diff label; same-cam boost dist/1.2 == d2/1.44 (monotone)
                float vn = same_cam ? d2 * (1.0f / 1.44f) : d2;
                if (vn < neg5[4]) ins_asc(neg5, vn);
            }
        }
    }
}

// merge the two half-row lists (adjacent lanes) and write fp16 5-lists.
// NOTE: snapshot partner lists BEFORE inserting — interleaved shfl/insert re-reads
// values the partner already absorbed (duplicate amplification bug, found R4).
__device__ __forceinline__ void emit_lists(float (&pos5)[5], float (&neg5)[5], int shalf,
        _Float16* posp, _Float16* negp, size_t gi, int slot) {
    float tp[5], tn[5];
#pragma unroll
    for (int k = 0; k < 5; ++k) { tp[k] = __shfl_xor(pos5[k], 1); tn[k] = __shfl_xor(neg5[k], 1); }
#pragma unroll
    for (int k = 0; k < 5; ++k) {
        if (tp[k] > pos5[4]) ins_desc(pos5, tp[k]);
        if (tn[k] < neg5[4]) ins_asc(neg5, tn[k]);
    }
    if (shalf == 0) {
        _Float16* pp = posp + (gi * KL_SYM + slot) * 5;
        _Float16* np = negp + (gi * KL_SYM + slot) * 5;
#pragma unroll
        for (int k = 0; k < 5; ++k) { pp[k] = (_Float16)pos5[k]; np[k] = (_Float16)neg5[k]; }
    }
}

// ---- kernel 2 (sym): one block per triangle tile (a,b), b<=a.
// As/Bs: row-major, 16B chunks XOR-swizzled by (row&7) -> frag ds_read_b128 hits
// all 32 banks 2-way (free) instead of 8 banks 8-way.  BK=64 halves barrier count.
// Dt (unioned over As/Bs) chunk-swizzled by (row&7) for the scan reads.
__global__ __launch_bounds__(256, 4) void k_gemm_sym(
        const unsigned short* __restrict__ xb, const float* __restrict__ sq,
        const int* __restrict__ labels, const int* __restrict__ camids,
        _Float16* __restrict__ posp, _Float16* __restrict__ negp) {
    __shared__ __align__(16) char smem[BM * DT_LD * 2 + 4 * BM * 4];
    unsigned short* As = (unsigned short*)smem;                 // [0, 16384)
    unsigned short* Bs = (unsigned short*)(smem + BM * BK * 2); // [16384, 32768)
    _Float16* Dt = (_Float16*)smem;                             // [0, 34816) aliases As/Bs
    float* sqr_s = (float*)(smem + BM * DT_LD * 2);
    float* sqc_s = sqr_s + BM;
    int* labcam_a = (int*)(sqc_s + BM);
    int* labcam_b = labcam_a + BM;

    const int tid = threadIdx.x;
    const int w = tid >> 6, lane = tid & 63;
    const int wm = w >> 1, wn = w & 1;

    // triangle decode: bx -> (a,b), b<=a
    int bx = blockIdx.x;
    int a = (int)((sqrtf(8.0f * (float)bx + 1.0f) - 1.0f) * 0.5f);
    while ((a + 1) * (a + 2) / 2 <= bx) ++a;
    while (a * (a + 1) / 2 > bx) --a;
    const int b = bx - a * (a + 1) / 2;
    const int r0 = a * BM, c0 = b * BM;

    if (tid < BM) {
        int gi = r0 + tid;
        sqr_s[tid] = sq[gi];
        labcam_a[tid] = (labels[gi] << 4) | camids[gi];
    } else {
        int t2 = tid - BM;
        int gj = c0 + t2;
        sqc_s[t2] = sq[gj];
        labcam_b[t2] = (labels[gj] << 4) | camids[gj];
    }
    __syncthreads();

    const int srow = tid >> 1;       // scan: 2 threads per row
    const int shalf = tid & 1;

    const int lr = lane >> 3;                 // staging: row within 8-row chunk
    const int lc = ((lane & 7) ^ lr) * 8;     // staging: swizzled source chunk * 8 halves
    const int m16 = lane & 15;
    const int quad = lane >> 4;
    const int s7 = m16 & 7;                   // frag-read swizzle key (= row&7)

    floatx4 acc[4][4];
#pragma unroll
    for (int mi = 0; mi < 4; ++mi)
#pragma unroll
        for (int ni = 0; ni < 4; ++ni) {
            floatx4 z = {0.f, 0.f, 0.f, 0.f};
            acc[mi][ni] = z;
        }

    for (int kk = 0; kk < NDIM; kk += BK) {
        __syncthreads();             // previous iter's LDS consumers done
#pragma unroll
        for (int q = 0; q < 4; ++q) {
            const int ra = w * 32 + q * 8;    // wave-uniform 8-row chunk base
            load_lds16(xb + (size_t)(r0 + ra + lr) * NDIM + kk + lc, As + ra * BK);
            load_lds16(xb + (size_t)(c0 + ra + lr) * NDIM + kk + lc, Bs + ra * BK);
        }
        __syncthreads();             // drains vmcnt(0): data in LDS
#pragma unroll
        for (int s = 0; s < 2; ++s) {         // two K=32 MFMA steps per BK=64 stage
            const int co = ((s * 4 + quad) ^ s7) * 8;   // swizzled chunk offset (halves)
            bf16x8 af[4], bfr[4];
#pragma unroll
            for (int mi = 0; mi < 4; ++mi)
                af[mi] = *(const bf16x8*)(As + (wm * 64 + mi * 16 + m16) * BK + co);
#pragma unroll
            for (int ni = 0; ni < 4; ++ni)
                bfr[ni] = *(const bf16x8*)(Bs + (wn * 64 + ni * 16 + m16) * BK + co);
#pragma unroll
            for (int mi = 0; mi < 4; ++mi)
#pragma unroll
                for (int ni = 0; ni < 4; ++ni)
                    acc[mi][ni] = __builtin_amdgcn_mfma_f32_16x16x32_bf16(af[mi], bfr[ni], acc[mi][ni], 0, 0, 0);
        }
    }
    __syncthreads();                 // all ds_reads of As/Bs done before Dt overwrite

    // ---- pass 1: d2 row-major (chunk-swizzled); scan rows of strip a ----
#pragma unroll
    for (int mi = 0; mi < 4; ++mi) {
        const int il = wm * 64 + mi * 16 + quad * 4;
#pragma unroll
        for (int ni = 0; ni < 4; ++ni) {
            const int jl = wn * 64 + ni * 16 + m16;
            const float sj = sqc_s[jl];
#pragma unroll
            for (int r = 0; r < 4; ++r) {
                float d2 = fmaxf(sqr_s[il + r] + sj - 2.0f * acc[mi][ni][r], 1e-12f);
                const int rw7 = (il + r) & 7;
                Dt[(il + r) * DT_LD + ((((jl >> 3) ^ rw7) << 3) | (jl & 7))] = (_Float16)d2;
            }
        }
    }
    __syncthreads();

    const float NINF = -__builtin_inff();
    const float PINF =  __builtin_inff();
    float pos5[5] = {NINF, NINF, NINF, NINF, NINF};
    float neg5[5] = {PINF, PINF, PINF, PINF, PINF};
    scan_half_row(Dt, labcam_b, srow, shalf, labcam_a[srow], pos5, neg5);
    emit_lists(pos5, neg5, shalf, posp, negp, (size_t)(r0 + srow), b);

    if (a != b) {
        __syncthreads();             // pass-1 scan reads done before Dt overwrite
        // ---- pass 2: d2 transposed (b64 packed, swizzled); scan rows of strip b ----
#pragma unroll
        for (int ni = 0; ni < 4; ++ni) {
            const int jl = wn * 64 + ni * 16 + m16;
            const float sj = sqc_s[jl];
            const int cw = jl & 7;
#pragma unroll
            for (int mi = 0; mi < 4; ++mi) {
                const int il = wm * 64 + mi * 16 + quad * 4;
                halfx4 h;
#pragma unroll
                for (int r = 0; r < 4; ++r)
                    h[r] = (_Float16)fmaxf(sqr_s[il + r] + sj - 2.0f * acc[mi][ni][r], 1e-12f);
                *(halfx4*)(Dt + jl * DT_LD + ((((il >> 3) ^ cw) << 3) | (il & 7))) = h;
            }
        }
        __syncthreads();
#pragma unroll
        for (int k = 0; k < 5; ++k) { pos5[k] = NINF; neg5[k] = PINF; }
        scan_half_row(Dt, labcam_a, srow, shalf, labcam_b[srow], pos5, neg5);
        emit_lists(pos5, neg5, shalf, posp, negp, (size_t)(c0 + srow), a);
    }
}

// ---- kernel 3: merge 64 fp16 d2-lists/row.  4 threads/row, 1024-thr blocks ----
__global__ __launch_bounds__(1024) void k_merge_sym(const _Float16* __restrict__ posp,
        const _Float16* __restrict__ negp, const int* __restrict__ epoch_p,
        float* __restrict__ out, float* __restrict__ wsum_p, float* __restrict__ wpsum_p) {
    const int t = threadIdx.x;
    const int rq = t & 3;                       // quarter of the row's 320 halves
    const int row = blockIdx.x * 256 + (t >> 2);
    const float NINF = -__builtin_inff(), PINF = __builtin_inff();
    float p5[5] = {NINF, NINF, NINF, NINF, NINF};
    float n5[5] = {PINF, PINF, PINF, PINF, PINF};
    const halfx8* pv8 = (const halfx8*)(posp + (size_t)row * (KL_SYM * 5) + rq * 80);
    const halfx8* nv8 = (const halfx8*)(negp + (size_t)row * (KL_SYM * 5) + rq * 80);
#pragma unroll
    for (int k = 0; k < 10; ++k) {
        halfx8 v = pv8[k];
#pragma unroll
        for (int e = 0; e < 8; ++e) { float f = (float)v[e]; if (f > p5[4]) ins_desc(p5, f); }
    }
#pragma unroll
    for (int k = 0; k < 10; ++k) {
        halfx8 v = nv8[k];
#pragma unroll
        for (int e = 0; e < 8; ++e) { float f = (float)v[e]; if (f < n5[4]) ins_asc(n5, f); }
    }
    // butterfly merge across the 4 lanes of this row (snapshot-then-insert)
#pragma unroll
    for (int o = 1; o <= 2; o <<= 1) {
        float tp[5], tn[5];
#pragma unroll
        for (int k = 0; k < 5; ++k) { tp[k] = __shfl_xor(p5[k], o); tn[k] = __shfl_xor(n5[k], o); }
#pragma unroll
        for (int k = 0; k < 5; ++k) {
            if (tp[k] > p5[4]) ins_desc(p5, tp[k]);
            if (tn[k] < n5[4]) ins_asc(n5, tn[k]);
        }
    }
    // d2 -> dist on the 5 survivors only
    float s = 0.f; int c = 0;
#pragma unroll
    for (int k = 0; k < 5; ++k) { bool fin = (p5[k] > NINF); s += fin ? sqrtf(p5[k]) : 0.f; c += fin ? 1 : 0; }
    float d_ap = (c > 0) ? s / (float)c : NINF;
    s = 0.f; c = 0;
#pragma unroll
    for (int k = 0; k < 5; ++k) { bool fin = (n5[k] < PINF); s += fin ? sqrtf(n5[k]) : 0.f; c += fin ? 1 : 0; }
    float d_an = (c > 0) ? s / (float)c : PINF;

    float w0 = 0.f, wp = 0.f;
    if (rq == 0) {
        out[1 + row] = d_ap;
        out[1 + NROW + row] = d_an;
        float diff = d_ap - d_an;
        w0 = 1.0f / (1.0f + expf(-2.0f * diff));         // sigmoid(ALPHA*(d_ap-d_an))
        float p;
        if (*epoch_p < 10) {
            p = fmaxf(diff, 0.0f) + log1pf(expf(-fabsf(diff)));  // stable softplus
        } else {
            p = fmaxf(diff + 0.3f, 0.0f);                // relu(d_ap - d_an + MARGIN)
        }
        wp = w0 * p;
    }
#pragma unroll
    for (int o = 32; o > 0; o >>= 1) { w0 += __shfl_down(w0, o); wp += __shfl_down(wp, o); }
    __shared__ float rw[16], rp[16];
    if ((t & 63) == 0) { rw[t >> 6] = w0; rp[t >> 6] = wp; }
    __syncthreads();
    if (t == 0) {
        float sw = 0.f, swp = 0.f;
#pragma unroll
        for (int i = 0; i < 16; ++i) { sw += rw[i]; swp += rp[i]; }
        wsum_p[blockIdx.x] = sw;
        wpsum_p[blockIdx.x] = swp;
    }
}

// ---- kernel 4: finalize loss scalar ----
__global__ void k_finalize(const float* __restrict__ wsum_p, const float* __restrict__ wpsum_p,
                           float* __restrict__ out) {
    if (threadIdx.x == 0) {
        float sw = 0.f, swp = 0.f;
        for (int i = 0; i < 32; ++i) { sw += wsum_p[i]; swp += wpsum_p[i]; }
        float M = fmaxf(sw / (float)NROW, 1e-12f);
        out[0] = swp / ((float)NROW * M);
    }
}

extern "C" void kernel_launch(void* const* d_in, const int* in_sizes, int n_in,
                              void* d_out, int out_size, void* d_ws, size_t ws_size,
                              hipStream_t stream) {
    const float* feats  = (const float*)d_in[0];
    const int*   labels = (const int*)d_in[1];
    const int*   camids = (const int*)d_in[2];
    const int*   epoch  = (const int*)d_in[3];
    float* out = (float*)d_out;
    char* ws = (char*)d_ws;

    // workspace layout (~44.07 MB, proven available in R4)
    unsigned short* xb = (unsigned short*)ws;                          // 33,554,432 B
    float* sq = (float*)(ws + 33554432);                               //     32,768 B
    const size_t HALF_LIST_BYTES = (size_t)NROW * KL_SYM * 5 * 2;      //  5,242,880 B
    _Float16* posp = (_Float16*)(ws + 33554432 + 32768);
    _Float16* negp = (_Float16*)(ws + 33554432 + 32768 + HALF_LIST_BYTES);
    float* wsum_p  = (float*)(ws + 33554432 + 32768 + 2 * HALF_LIST_BYTES);
    float* wpsum_p = wsum_p + 32;

    k_normalize<<<NROW, 256, 0, stream>>>(feats, xb, sq);
    k_gemm_sym<<<NTILE, 256, 0, stream>>>(xb, sq, labels, camids, posp, negp);
    k_merge_sym<<<NROW / 256, 1024, 0, stream>>>(posp, negp, epoch, out, wsum_p, wpsum_p);
    k_finalize<<<1, 64, 0, stream>>>(wsum_p, wpsum_p, out);
}